// Round 14
// baseline (425.079 us; speedup 1.0000x reference)
//
#include <hip/hip_runtime.h>
#include <stdint.h>

#define Bb 8
#define Ss 2048
#define Hh 16
#define Aa 128
#define Dd 128
#define NGATE 384
#define KDIM 256
#define NCH 16
#define CLEN 128
#define ROWS (Bb*Ss)
#define ROWSTR (Hh*Aa)

typedef float f32x4 __attribute__((ext_vector_type(4)));
typedef __bf16 bf16x8 __attribute__((ext_vector_type(8)));
typedef unsigned short u16x8 __attribute__((ext_vector_type(8)));

static __device__ __forceinline__ unsigned short f2bf(float f){
  unsigned int u = __builtin_bit_cast(unsigned int, f);
  u += 0x7FFFu + ((u >> 16) & 1u);
  return (unsigned short)(u >> 16);
}
static __device__ __forceinline__ float bf2f(unsigned short s){
  unsigned int u = ((unsigned int)s) << 16;
  return __builtin_bit_cast(float, u);
}
static __device__ __forceinline__ float sigf(float x){ return 1.0f/(1.0f + __expf(-x)); }

// ---- w_hid -> [hy=h*2+nh][chunk=(wn*8+ks)*3+g][lane][kb] bf16 (R8/R12 layout) ----
__global__ void k_conv_whid(const float* __restrict__ w, unsigned short* __restrict__ wt){
  int idx = blockIdx.x*256 + threadIdx.x;
  const int total = Hh*KDIM*NGATE;
  for (; idx < total; idx += gridDim.x*256){
    int o = idx % NGATE; int k = (idx/NGATE) % KDIM; int h = idx/(NGATE*KDIM);
    int g = o >> 7, d = o & 127;
    int nh = d >> 6, dl = d & 63;
    int wn = dl >> 4, ln15 = d & 15;
    int ks = k >> 5, lq = (k >> 3) & 3, kb = k & 7;
    int hy = h*2 + nh;
    int l = lq*16 + ln15;
    size_t dst = (size_t)hy*(192*KDIM) + (size_t)((((wn*8 + ks)*3 + g)*64 + l)*8 + kb);
    wt[dst] = f2bf(w[idx]);
  }
}
// ---- w_og -> [h][chunk=(wn*8+ks)*2+j][lane][kb] bf16 (wave-coalesced fragments) ----
__global__ void k_conv_wog(const float* __restrict__ w, unsigned short* __restrict__ wt){
  int idx = blockIdx.x*256 + threadIdx.x;
  const int total = Hh*KDIM*Dd;
  for (; idx < total; idx += gridDim.x*256){
    int o = idx % Dd; int k = (idx/Dd) % KDIM; int h = idx/(Dd*KDIM);
    int wn = o >> 5, j = (o >> 4) & 1, ln15 = o & 15;
    int ks = k >> 5, lq = (k >> 3) & 3, kb = k & 7;
    int lane = lq*16 + ln15;
    size_t dst = (size_t)h*(Dd*KDIM) + (size_t)((((wn*8 + ks)*2 + j)*64 + lane)*8 + kb);
    wt[dst] = f2bf(w[idx]);
  }
}

// ---- cumsum pass A: read fp32 x ONCE -> chunk totals (fp32) + xbf (bf16) ----
__global__ void k_cumsum_a(const float* __restrict__ x, float* __restrict__ totals,
                           unsigned short* __restrict__ xbf){
  int c = blockIdx.x;
  int k = c % NCH; int hb = c / NCH;
  int b = hb / Hh, h = hb % Hh;
  int a = threadIdx.x;
  const size_t base = ((size_t)(b*Ss + k*CLEN)*Hh + h)*Aa + a;
  const float* p = x + base;
  unsigned short* xq = xbf + base;
  float run = 0.f;
  #pragma unroll 2
  for (int i = 0; i < CLEN; ++i){
    float v = p[(size_t)i*ROWSTR];
    run += v;
    xq[(size_t)i*ROWSTR] = f2bf(v);
  }
  totals[(size_t)c*Aa + a] = run;
}

// ---- cumsum pass C: re-read bf16 xbf; fp32 chunk carries ----
__global__ void k_cumsum_c(const unsigned short* __restrict__ xbf, const float* __restrict__ totals,
                           unsigned short* __restrict__ csum){
  int c = blockIdx.x;
  int k = c % NCH; int hb = c / NCH;
  int b = hb / Hh, h = hb % Hh;
  int a = threadIdx.x;
  const float* tp = totals + (size_t)hb*NCH*Aa + a;
  float run = 0.f;
  for (int j = 0; j < k; ++j) run += tp[(size_t)j*Aa];
  const size_t base = ((size_t)(b*Ss + k*CLEN)*Hh + h)*Aa + a;
  const unsigned short* p = xbf + base;
  unsigned short* q = csum + base;
  #pragma unroll 2
  for (int i = 0; i < CLEN; ++i){
    run += bf2f(p[(size_t)i*ROWSTR]);
    q[(size_t)i*ROWSTR] = f2bf(run);
  }
}

// ---- LN stats + APPLY in place on csum (per (b,s) row over H*A = 2048) ----
__global__ void k_stats_ln(unsigned short* __restrict__ cs,
                           const float* __restrict__ ln_g, const float* __restrict__ ln_b){
  int r = blockIdx.x;
  int t = threadIdx.x;                      // 256
  unsigned short* p = cs + (size_t)r*ROWSTR + t*8;
  u16x8 v = *(const u16x8*)p;
  float s = 0.f, q = 0.f;
  #pragma unroll
  for (int i = 0; i < 8; ++i){ float f = bf2f(v[i]); s += f; q += f*f; }
  #pragma unroll
  for (int off = 32; off; off >>= 1){ s += __shfl_down(s, off); q += __shfl_down(q, off); }
  __shared__ float ls[4], lq[4];
  __shared__ float2 mrs;
  int wid = t >> 6, lane = t & 63;
  if (lane == 0){ ls[wid] = s; lq[wid] = q; }
  __syncthreads();
  if (t == 0){
    float S2 = ls[0]+ls[1]+ls[2]+ls[3], Q = lq[0]+lq[1]+lq[2]+lq[3];
    float mu = S2 * (1.0f/(float)ROWSTR);
    float var = Q * (1.0f/(float)ROWSTR) - mu*mu;
    mrs = make_float2(mu, rsqrtf(var + 1e-6f));
  }
  __syncthreads();
  float mu = mrs.x, rstd = mrs.y;
  const float4* g4 = (const float4*)(ln_g + t*8);
  const float4* b4 = (const float4*)(ln_b + t*8);
  float4 g0 = g4[0], g1 = g4[1], b0 = b4[0], b1 = b4[1];
  u16x8 o;
  o[0] = f2bf((bf2f(v[0]) - mu)*rstd*g0.x + b0.x);
  o[1] = f2bf((bf2f(v[1]) - mu)*rstd*g0.y + b0.y);
  o[2] = f2bf((bf2f(v[2]) - mu)*rstd*g0.z + b0.z);
  o[3] = f2bf((bf2f(v[3]) - mu)*rstd*g0.w + b0.w);
  o[4] = f2bf((bf2f(v[4]) - mu)*rstd*g1.x + b1.x);
  o[5] = f2bf((bf2f(v[5]) - mu)*rstd*g1.y + b1.y);
  o[6] = f2bf((bf2f(v[6]) - mu)*rstd*g1.z + b1.z);
  o[7] = f2bf((bf2f(v[7]) - mu)*rstd*g1.w + b1.w);
  *(u16x8*)p = o;
}

// ---- gates GEMM v11: R12 L2 mapping (192 cols/block, hy=32), 2 blocks/CU ----
// grid (16, 32): mg covers 8 tiles, hy=h*2+nh. 512 thr = 8 waves as 2m(64r) x 4n(48c).
// Bf holds only the CURRENT K-half (48 VGPR), reloaded from L2-hot wht per half.
#define GROWT(t_) ((mg*8 + (t_))*128)
__launch_bounds__(512, 4)
__global__ void k_gates(const unsigned short* __restrict__ xbf,
                        const unsigned short* __restrict__ csln,
                        const unsigned short* __restrict__ wht,
                        const float* __restrict__ b_hid, unsigned int* __restrict__ fu){
  __shared__ unsigned short lA[2][128*64];     // 2 x 16 KiB, XOR-swizzled
  const int mg = blockIdx.x, hy = blockIdx.y;
  const int h = hy >> 1, nh = hy & 1;
  const int tid = threadIdx.x;
  const int lane = tid & 63, wid = tid >> 6;
  const int wm = wid & 1, wn = wid >> 1;       // 2m x 4n
  const int ln15 = lane & 15, lq = lane >> 4;
  const int r0 = tid >> 3, q0 = tid & 7;
  const int lwA0 = (r0*128 + q0*16) ^ ((r0 & 7) << 4);
  const int lwA1 = ((r0+64)*128 + q0*16) ^ ((r0 & 7) << 4);
  const u16x8* bs8 = (const u16x8*)(wht + (size_t)hy*(192*KDIM));

  const int dcol = nh*64 + wn*16 + ln15;
  const float big = b_hid[h*NGATE + dcol];
  const float bfg = b_hid[h*NGATE + 128 + dcol];
  const float bhd = b_hid[h*NGATE + 256 + dcol];

  bf16x8 Bf[4][3];                             // current K-half only: 48 VGPR
  f32x4 acc[4][3];
  #pragma unroll
  for (int i = 0; i < 4; ++i)
    #pragma unroll
    for (int j = 0; j < 3; ++j) acc[i][j] = (f32x4){0.f,0.f,0.f,0.f};

  u16x8 pa0, pa1;

#define GB_LOAD(half_) do { \
    _Pragma("unroll") \
    for (int sl_ = 0; sl_ < 4; ++sl_) \
      _Pragma("unroll") \
      for (int g_ = 0; g_ < 3; ++g_) \
        Bf[sl_][g_] = __builtin_bit_cast(bf16x8, \
          bs8[((wn*8 + (half_)*4 + sl_)*3 + g_)*64 + lane]); \
  } while(0)
#define GA_FETCH(t_, kk_) do { \
    const unsigned short* as_ = ((kk_) < 2) ? xbf : csln; \
    const size_t base_ = (size_t)(GROWT(t_) + r0)*ROWSTR + h*Aa + ((kk_) & 1)*64 + q0*8; \
    pa0 = *(const u16x8*)(as_ + base_); \
    pa1 = *(const u16x8*)(as_ + base_ + (size_t)64*ROWSTR); \
  } while(0)
#define GA_WRITE(buf_) do { \
    *(u16x8*)((char*)lA[buf_] + lwA0) = pa0; \
    *(u16x8*)((char*)lA[buf_] + lwA1) = pa1; \
  } while(0)

  // prologue
  GA_FETCH(0, 0); GA_WRITE(0);
  GA_FETCH(0, 1);

  for (int t = 0; t < 8; ++t){
    #pragma unroll
    for (int kk = 0; kk < 4; ++kk){            // cur = kk&1 (compile-time)
      const int cur = kk & 1;
      __syncthreads();
      if (kk == 0) GB_LOAD(0);                 // reload B K-half from L2
      if (kk == 2) GB_LOAD(1);
      if (kk < 3){
        GA_WRITE(cur^1);
        if (kk + 2 < 4) GA_FETCH(t, kk+2);
        else if (t + 1 < 8) GA_FETCH(t+1, 0);
      } else if (t + 1 < 8){
        GA_WRITE(cur^1);
        GA_FETCH(t+1, 1);
      }
      #pragma unroll
      for (int ks2 = 0; ks2 < 2; ++ks2){
        const int kel = ks2*32 + lq*8;
        bf16x8 af[4];
        #pragma unroll
        for (int mf = 0; mf < 4; ++mf){
          int ra = wm*64 + mf*16 + ln15;
          af[mf] = __builtin_bit_cast(bf16x8,
            *(const u16x8*)((const char*)lA[cur] + ((ra*128 + kel*2) ^ ((ra & 7) << 4))));
        }
        #pragma unroll
        for (int g = 0; g < 3; ++g)
          #pragma unroll
          for (int mf = 0; mf < 4; ++mf)
            acc[mf][g] = __builtin_amdgcn_mfma_f32_16x16x32_bf16(
                af[mf], Bf[(kk & 1)*2 + ks2][g], acc[mf][g], 0, 0, 0);
      }
      if (kk == 3){
        const int m0 = GROWT(t);
        #pragma unroll
        for (int mf = 0; mf < 4; ++mf){
          const int rowb = m0 + wm*64 + mf*16 + lq*4;
          f32x4 aig = acc[mf][0], afg = acc[mf][1], ahd = acc[mf][2];
          #pragma unroll
          for (int r = 0; r < 4; ++r){
            float fg = sigf(afg[r] + bfg);
            float uu = sigf(aig[r] + big) * fmaxf(ahd[r] + bhd, 0.0f);
            fu[(size_t)(rowb + r)*ROWSTR + h*Dd + dcol] =
              ((unsigned int)f2bf(uu) << 16) | (unsigned int)f2bf(fg);
          }
          acc[mf][0] = (f32x4){0.f,0.f,0.f,0.f};
          acc[mf][1] = (f32x4){0.f,0.f,0.f,0.f};
          acc[mf][2] = (f32x4){0.f,0.f,0.f,0.f};
        }
      }
    }
  }
#undef GB_LOAD
#undef GA_FETCH
#undef GA_WRITE
}

// ---- recurrence pass A: per-128-chunk (F, C) ----
__global__ void k_recur_a(const unsigned int* __restrict__ fu,
                          float* __restrict__ Fc, float* __restrict__ Cc){
  int c = blockIdx.x;
  int k = c % NCH; int hb = c / NCH;
  int b = hb / Hh, h = hb % Hh;
  int d = threadIdx.x;
  const unsigned int* p = fu + ((size_t)(b*Ss + k*CLEN)*Hh + h)*Dd + d;
  float F = 1.f, C = 0.f;
  #pragma unroll 4
  for (int i = 0; i < CLEN; ++i){
    unsigned int v = p[(size_t)i*ROWSTR];
    float f = bf2f((unsigned short)v);
    float u = bf2f((unsigned short)(v >> 16));
    C = fmaf(f, C, u);
    F *= f;
  }
  Fc[(size_t)c*Dd + d] = F;
  Cc[(size_t)c*Dd + d] = C;
}

// ---- recurrence pass B: carry BEFORE each chunk ----
__global__ void k_recur_b(const float* __restrict__ Fc, const float* __restrict__ Cc,
                          const float* __restrict__ init_cx, float* __restrict__ gcarry){
  int bh = blockIdx.x;
  int h = bh % Hh;
  int d = threadIdx.x;
  float carry = init_cx[h*Dd + d];
  for (int j = 0; j < NCH; ++j){
    size_t o = ((size_t)bh*NCH + j)*Dd + d;
    gcarry[o] = carry;
    carry = fmaf(Fc[o], carry, Cc[o]);
  }
}

// ---- fused recurrence + og GEMM + gating (R12 v2, unchanged) ----
#define CPITCH 132
#define XPITCH 136
__launch_bounds__(512, 4)
__global__ void k_og_fused(const unsigned short* __restrict__ xbf,
                           const unsigned int* __restrict__ fu,
                           const unsigned short* __restrict__ wog2,
                           const float* __restrict__ gcarry,
                           const float* __restrict__ b_og, float* __restrict__ out){
  __shared__ float s_cell[64*CPITCH];
  __shared__ unsigned short s_xa[64*XPITCH];
  __shared__ float2 s_scan[4*128];
  __shared__ float s_cc[128];
  const int mg = blockIdx.x;    // 32
  const int h  = blockIdx.y;    // 16
  const int tid = threadIdx.x;
  const int lane = tid & 63, wid = tid >> 6;
  const int wm = wid >> 2, wn = wid & 3;
  const int ln15 = lane & 15, lq = lane >> 4;
  const int rd = tid & 127, rq = tid >> 7;

  bf16x8 Bf[8][2];
  {
    const u16x8* bs8 = (const u16x8*)(wog2 + (size_t)h*(Dd*KDIM));
    #pragma unroll
    for (int ks = 0; ks < 8; ++ks)
      #pragma unroll
      for (int j = 0; j < 2; ++j)
        Bf[ks][j] = __builtin_bit_cast(bf16x8, bs8[((wn*8 + ks)*2 + j)*64 + lane]);
  }
  if (tid < 128)
    s_cc[tid] = gcarry[((size_t)((mg>>2)*Hh + h)*NCH + (mg & 3)*4)*Dd + tid];
  __syncthreads();

  f32x4 acc[2][2];
  #pragma unroll
  for (int i = 0; i < 2; ++i){ acc[i][0] = (f32x4){0,0,0,0}; acc[i][1] = (f32x4){0,0,0,0}; }

  for (int t = 0; t < 8; ++t){
    const int row0 = mg*512 + t*64;
    unsigned int uf[16];
    const unsigned int* fp = fu + (size_t)(row0 + rq*16)*ROWSTR + h*Dd + rd;
    #pragma unroll
    for (int i = 0; i < 16; ++i) uf[i] = fp[(size_t)i*ROWSTR];
    #pragma unroll
    for (int i = 0; i < 2; ++i){
      int c = tid + i*512;
      int r = c >> 4, c8 = c & 15;
      *(u16x8*)&s_xa[r*XPITCH + c8*8] =
        *(const u16x8*)(xbf + (size_t)(row0 + r)*ROWSTR + h*Aa + c8*8);
    }
    float F = 1.f, C = 0.f;
    #pragma unroll
    for (int i = 0; i < 16; ++i){
      float f = bf2f((unsigned short)uf[i]);
      float u = bf2f((unsigned short)(uf[i] >> 16));
      C = fmaf(f, C, u); F *= f;
    }
    s_scan[rq*128 + rd] = make_float2(F, C);
    __syncthreads();
    float cin = s_cc[rd];
    #pragma unroll
    for (int qq = 0; qq < 3; ++qq){
      if (rq > qq){ float2 s = s_scan[qq*128 + rd]; cin = fmaf(s.x, cin, s.y); }
    }
    __syncthreads();
    if (rq == 3){ float2 s3 = s_scan[3*128 + rd]; s_cc[rd] = fmaf(s3.x, cin, s3.y); }
    {
      float c = cin;
      #pragma unroll
      for (int i = 0; i < 16; ++i){
        float f = bf2f((unsigned short)uf[i]);
        float u = bf2f((unsigned short)(uf[i] >> 16));
        c = fmaf(f, c, u);
        s_cell[(rq*16 + i)*CPITCH + rd] = c;
      }
    }
    __syncthreads();
    #pragma unroll
    for (int ks = 0; ks < 4; ++ks){
      bf16x8 af[2];
      #pragma unroll
      for (int mf = 0; mf < 2; ++mf){
        int ra = wm*32 + mf*16 + ln15;
        af[mf] = __builtin_bit_cast(bf16x8,
          *(const u16x8*)&s_xa[ra*XPITCH + ks*32 + lq*8]);
      }
      #pragma unroll
      for (int mf = 0; mf < 2; ++mf)
        #pragma unroll
        for (int j = 0; j < 2; ++j)
          acc[mf][j] = __builtin_amdgcn_mfma_f32_16x16x32_bf16(af[mf], Bf[ks][j], acc[mf][j], 0, 0, 0);
    }
    #pragma unroll
    for (int ks = 4; ks < 8; ++ks){
      bf16x8 af[2];
      #pragma unroll
      for (int mf = 0; mf < 2; ++mf){
        int ra = wm*32 + mf*16 + ln15;
        const float* cp = &s_cell[ra*CPITCH + (ks-4)*32 + lq*8];
        f32x4 c0 = *(const f32x4*)cp;
        f32x4 c1 = *(const f32x4*)(cp + 4);
        u16x8 tt;
        tt[0]=f2bf(c0[0]); tt[1]=f2bf(c0[1]); tt[2]=f2bf(c0[2]); tt[3]=f2bf(c0[3]);
        tt[4]=f2bf(c1[0]); tt[5]=f2bf(c1[1]); tt[6]=f2bf(c1[2]); tt[7]=f2bf(c1[3]);
        af[mf] = __builtin_bit_cast(bf16x8, tt);
      }
      #pragma unroll
      for (int mf = 0; mf < 2; ++mf)
        #pragma unroll
        for (int j = 0; j < 2; ++j)
          acc[mf][j] = __builtin_amdgcn_mfma_f32_16x16x32_bf16(af[mf], Bf[ks][j], acc[mf][j], 0, 0, 0);
    }
    #pragma unroll
    for (int mf = 0; mf < 2; ++mf){
      const int rl = wm*32 + mf*16 + lq*4;
      #pragma unroll
      for (int j = 0; j < 2; ++j){
        const int d = wn*32 + j*16 + ln15;
        const float bo = b_og[h*Dd + d];
        #pragma unroll
        for (int r = 0; r < 4; ++r){
          float cell = s_cell[(rl + r)*CPITCH + d];
          out[(size_t)(row0 + rl + r)*ROWSTR + h*Dd + d] = sigf(acc[mf][j][r] + bo) * cell;
        }
        acc[mf][j] = (f32x4){0.f,0.f,0.f,0.f};
      }
    }
    __syncthreads();
  }
}

extern "C" void kernel_launch(void* const* d_in, const int* in_sizes, int n_in,
                              void* d_out, int out_size, void* d_ws, size_t ws_size,
                              hipStream_t stream){
  const float* x       = (const float*)d_in[0];
  const float* w_hid   = (const float*)d_in[1];
  const float* b_hid   = (const float*)d_in[2];
  const float* w_og    = (const float*)d_in[3];
  const float* b_og    = (const float*)d_in[4];
  const float* ln_g    = (const float*)d_in[5];
  const float* ln_b    = (const float*)d_in[6];
  const float* init_cx = (const float*)d_in[7];
  float* out = (float*)d_out;

  char* ws = (char*)d_ws;
  unsigned short* csum = (unsigned short*)(ws);                       // 64 MiB
  unsigned int*   fu   = (unsigned int*)  (ws + ((size_t)64  << 20)); // 128 MiB
  unsigned short* xbf  = (unsigned short*)(ws + ((size_t)192 << 20)); // 64 MiB
  float*          tot  = (float*)         (ws + ((size_t)256 << 20)); // 1 MiB
  float*          Fc   = (float*)         (ws + ((size_t)257 << 20)); // 1 MiB
  float*          Cc   = (float*)         (ws + ((size_t)258 << 20)); // 1 MiB
  unsigned short* wht  = (unsigned short*)(ws + ((size_t)260 << 20)); // 3 MiB
  unsigned short* wot  = (unsigned short*)(ws + ((size_t)263 << 20)); // 1 MiB
  float*          gcar = (float*)         (ws + ((size_t)264 << 20)); // 1 MiB

  k_conv_whid<<<2048, 256, 0, stream>>>(w_hid, wht);
  k_conv_wog <<<1024, 256, 0, stream>>>(w_og,  wot);
  k_cumsum_a <<<Bb*Hh*NCH, Aa, 0, stream>>>(x, tot, xbf);
  k_cumsum_c <<<Bb*Hh*NCH, Aa, 0, stream>>>(xbf, tot, csum);
  k_stats_ln <<<ROWS, 256, 0, stream>>>(csum, ln_g, ln_b);
  k_gates    <<<dim3(16, 32), 512, 0, stream>>>(xbf, csum, wht, b_hid, fu);
  k_recur_a  <<<Bb*Hh*NCH, Dd, 0, stream>>>(fu, Fc, Cc);
  k_recur_b  <<<Bb*Hh, Dd, 0, stream>>>(Fc, Cc, init_cx, gcar);
  k_og_fused <<<dim3(32, 16), 512, 0, stream>>>(xbf, fu, wot, gcar, b_og, out);
}

// Round 15
// 309.931 us; speedup vs baseline: 1.3715x; 1.3715x over previous
//
#include <hip/hip_runtime.h>
#include <stdint.h>

#define Bb 8
#define Ss 2048
#define Hh 16
#define Aa 128
#define Dd 128
#define NGATE 384
#define KDIM 256
#define NCH 16
#define CLEN 128
#define ROWS (Bb*Ss)
#define ROWSTR (Hh*Aa)

typedef float f32x4 __attribute__((ext_vector_type(4)));
typedef __bf16 bf16x8 __attribute__((ext_vector_type(8)));
typedef unsigned short u16x8 __attribute__((ext_vector_type(8)));

static __device__ __forceinline__ unsigned short f2bf(float f){
  unsigned int u = __builtin_bit_cast(unsigned int, f);
  u += 0x7FFFu + ((u >> 16) & 1u);
  return (unsigned short)(u >> 16);
}
static __device__ __forceinline__ float bf2f(unsigned short s){
  unsigned int u = ((unsigned int)s) << 16;
  return __builtin_bit_cast(float, u);
}
static __device__ __forceinline__ float sigf(float x){ return 1.0f/(1.0f + __expf(-x)); }
// pack two f32 -> (bf16(hi)<<16)|bf16(lo), RNE — single HW instr
static __device__ __forceinline__ unsigned int pk_bf16(float lo, float hi){
  unsigned int r;
  asm("v_cvt_pk_bf16_f32 %0, %1, %2" : "=v"(r) : "v"(lo), "v"(hi));
  return r;
}

// ---- w_hid -> [hy=h*2+nh][chunk=(wn*8+ks)*3+g][lane][kb] bf16 (R8 layout) ----
__global__ void k_conv_whid(const float* __restrict__ w, unsigned short* __restrict__ wt){
  int idx = blockIdx.x*256 + threadIdx.x;
  const int total = Hh*KDIM*NGATE;
  for (; idx < total; idx += gridDim.x*256){
    int o = idx % NGATE; int k = (idx/NGATE) % KDIM; int h = idx/(NGATE*KDIM);
    int g = o >> 7, d = o & 127;
    int nh = d >> 6, dl = d & 63;
    int wn = dl >> 4, ln15 = d & 15;
    int ks = k >> 5, lq = (k >> 3) & 3, kb = k & 7;
    int hy = h*2 + nh;
    int l = lq*16 + ln15;
    size_t dst = (size_t)hy*(192*KDIM) + (size_t)((((wn*8 + ks)*3 + g)*64 + l)*8 + kb);
    wt[dst] = f2bf(w[idx]);
  }
}
// ---- w_og -> [h][chunk=(wn*8+ks)*2+j][lane][kb] bf16 (wave-coalesced fragments) ----
__global__ void k_conv_wog(const float* __restrict__ w, unsigned short* __restrict__ wt){
  int idx = blockIdx.x*256 + threadIdx.x;
  const int total = Hh*KDIM*Dd;
  for (; idx < total; idx += gridDim.x*256){
    int o = idx % Dd; int k = (idx/Dd) % KDIM; int h = idx/(Dd*KDIM);
    int wn = o >> 5, j = (o >> 4) & 1, ln15 = o & 15;
    int ks = k >> 5, lq = (k >> 3) & 3, kb = k & 7;
    int lane = lq*16 + ln15;
    size_t dst = (size_t)h*(Dd*KDIM) + (size_t)((((wn*8 + ks)*2 + j)*64 + lane)*8 + kb);
    wt[dst] = f2bf(w[idx]);
  }
}

// ---- cumsum pass A: read fp32 x ONCE -> chunk totals (fp32) + xbf (bf16) ----
__global__ void k_cumsum_a(const float* __restrict__ x, float* __restrict__ totals,
                           unsigned short* __restrict__ xbf){
  int c = blockIdx.x;
  int k = c % NCH; int hb = c / NCH;
  int b = hb / Hh, h = hb % Hh;
  int a = threadIdx.x;
  const size_t base = ((size_t)(b*Ss + k*CLEN)*Hh + h)*Aa + a;
  const float* p = x + base;
  unsigned short* xq = xbf + base;
  float run = 0.f;
  #pragma unroll 2
  for (int i = 0; i < CLEN; ++i){
    float v = p[(size_t)i*ROWSTR];
    run += v;
    xq[(size_t)i*ROWSTR] = f2bf(v);
  }
  totals[(size_t)c*Aa + a] = run;
}

// ---- cumsum pass C: re-read bf16 xbf; fp32 chunk carries ----
__global__ void k_cumsum_c(const unsigned short* __restrict__ xbf, const float* __restrict__ totals,
                           unsigned short* __restrict__ csum){
  int c = blockIdx.x;
  int k = c % NCH; int hb = c / NCH;
  int b = hb / Hh, h = hb % Hh;
  int a = threadIdx.x;
  const float* tp = totals + (size_t)hb*NCH*Aa + a;
  float run = 0.f;
  for (int j = 0; j < k; ++j) run += tp[(size_t)j*Aa];
  const size_t base = ((size_t)(b*Ss + k*CLEN)*Hh + h)*Aa + a;
  const unsigned short* p = xbf + base;
  unsigned short* q = csum + base;
  #pragma unroll 2
  for (int i = 0; i < CLEN; ++i){
    run += bf2f(p[(size_t)i*ROWSTR]);
    q[(size_t)i*ROWSTR] = f2bf(run);
  }
}

// ---- LN stats + APPLY in place on csum (per (b,s) row over H*A = 2048) ----
__global__ void k_stats_ln(unsigned short* __restrict__ cs,
                           const float* __restrict__ ln_g, const float* __restrict__ ln_b){
  int r = blockIdx.x;
  int t = threadIdx.x;                      // 256
  unsigned short* p = cs + (size_t)r*ROWSTR + t*8;
  u16x8 v = *(const u16x8*)p;
  float s = 0.f, q = 0.f;
  #pragma unroll
  for (int i = 0; i < 8; ++i){ float f = bf2f(v[i]); s += f; q += f*f; }
  #pragma unroll
  for (int off = 32; off; off >>= 1){ s += __shfl_down(s, off); q += __shfl_down(q, off); }
  __shared__ float ls[4], lq[4];
  __shared__ float2 mrs;
  int wid = t >> 6, lane = t & 63;
  if (lane == 0){ ls[wid] = s; lq[wid] = q; }
  __syncthreads();
  if (t == 0){
    float S2 = ls[0]+ls[1]+ls[2]+ls[3], Q = lq[0]+lq[1]+lq[2]+lq[3];
    float mu = S2 * (1.0f/(float)ROWSTR);
    float var = Q * (1.0f/(float)ROWSTR) - mu*mu;
    mrs = make_float2(mu, rsqrtf(var + 1e-6f));
  }
  __syncthreads();
  float mu = mrs.x, rstd = mrs.y;
  const float4* g4 = (const float4*)(ln_g + t*8);
  const float4* b4 = (const float4*)(ln_b + t*8);
  float4 g0 = g4[0], g1 = g4[1], b0 = b4[0], b1 = b4[1];
  u16x8 o;
  o[0] = f2bf((bf2f(v[0]) - mu)*rstd*g0.x + b0.x);
  o[1] = f2bf((bf2f(v[1]) - mu)*rstd*g0.y + b0.y);
  o[2] = f2bf((bf2f(v[2]) - mu)*rstd*g0.z + b0.z);
  o[3] = f2bf((bf2f(v[3]) - mu)*rstd*g0.w + b0.w);
  o[4] = f2bf((bf2f(v[4]) - mu)*rstd*g1.x + b1.x);
  o[5] = f2bf((bf2f(v[5]) - mu)*rstd*g1.y + b1.y);
  o[6] = f2bf((bf2f(v[6]) - mu)*rstd*g1.z + b1.z);
  o[7] = f2bf((bf2f(v[7]) - mu)*rstd*g1.w + b1.w);
  *(u16x8*)p = o;
}

// ---- gates GEMM v9 (R12 exact) + cvt_pk epilogue pack ----
// grid (8, 32): mg, hy=h*2+nh. 512 thr = 8 waves as 2m(64 rows) x 4n(48 cols).
#define GROWT(t_) ((mg*16 + (t_))*128)
__launch_bounds__(512, 2)
__global__ void k_gates(const unsigned short* __restrict__ xbf,
                        const unsigned short* __restrict__ csln,
                        const unsigned short* __restrict__ wht,
                        const float* __restrict__ b_hid, unsigned int* __restrict__ fu){
  __shared__ unsigned short lA[4][128*64];     // 4 x 16 KiB, XOR-swizzled
  const int mg = blockIdx.x, hy = blockIdx.y;
  const int h = hy >> 1, nh = hy & 1;
  const int tid = threadIdx.x;
  const int lane = tid & 63, wid = tid >> 6;
  const int wm = wid & 1, wn = wid >> 1;       // 2m x 4n
  const int ln15 = lane & 15, lq = lane >> 4;
  const int r0 = tid >> 3, q0 = tid & 7;
  const int lwA0 = (r0*128 + q0*16) ^ ((r0 & 7) << 4);
  const int lwA1 = ((r0+64)*128 + q0*16) ^ ((r0 & 7) << 4);

  bf16x8 Bf[8][3];
  {
    const u16x8* bs8 = (const u16x8*)(wht + (size_t)hy*(192*KDIM));
    #pragma unroll
    for (int ks = 0; ks < 8; ++ks)
      #pragma unroll
      for (int g = 0; g < 3; ++g)
        Bf[ks][g] = __builtin_bit_cast(bf16x8, bs8[((wn*8 + ks)*3 + g)*64 + lane]);
  }
  const int dcol = nh*64 + wn*16 + ln15;
  const float big = b_hid[h*NGATE + dcol];
  const float bfg = b_hid[h*NGATE + 128 + dcol];
  const float bhd = b_hid[h*NGATE + 256 + dcol];

  f32x4 acc[4][3];
  #pragma unroll
  for (int i = 0; i < 4; ++i)
    #pragma unroll
    for (int j = 0; j < 3; ++j) acc[i][j] = (f32x4){0.f,0.f,0.f,0.f};

  u16x8 pa0, pa1, pa2, pa3;

#define GA_FETCH(t_, half_) do { \
    const unsigned short* as_ = (half_) ? csln : xbf; \
    const size_t base_ = (size_t)(GROWT(t_) + r0)*ROWSTR + h*Aa + q0*8; \
    pa0 = *(const u16x8*)(as_ + base_); \
    pa1 = *(const u16x8*)(as_ + base_ + (size_t)64*ROWSTR); \
    pa2 = *(const u16x8*)(as_ + base_ + 64); \
    pa3 = *(const u16x8*)(as_ + base_ + 64 + (size_t)64*ROWSTR); \
  } while(0)
#define GA_WRITE(bp_) do { \
    *(u16x8*)((char*)lA[(bp_)*2+0] + lwA0) = pa0; \
    *(u16x8*)((char*)lA[(bp_)*2+0] + lwA1) = pa1; \
    *(u16x8*)((char*)lA[(bp_)*2+1] + lwA0) = pa2; \
    *(u16x8*)((char*)lA[(bp_)*2+1] + lwA1) = pa3; \
  } while(0)

  GA_FETCH(0, 0); GA_WRITE(0);
  GA_FETCH(0, 1);

  for (int t = 0; t < 16; ++t){
    #pragma unroll
    for (int half = 0; half < 2; ++half){
      __syncthreads();
      if (half == 0){
        GA_WRITE(1);
        GA_FETCH(t+1 < 16 ? t+1 : t, 0);
      } else if (t + 1 < 16){
        GA_WRITE(0);
        GA_FETCH(t+1, 1);
      }
      #pragma unroll
      for (int kk2 = 0; kk2 < 2; ++kk2){
        #pragma unroll
        for (int ks2 = 0; ks2 < 2; ++ks2){
          const int kel = ks2*32 + lq*8;
          bf16x8 af[4];
          #pragma unroll
          for (int mf = 0; mf < 4; ++mf){
            int ra = wm*64 + mf*16 + ln15;
            af[mf] = __builtin_bit_cast(bf16x8,
              *(const u16x8*)((const char*)lA[half*2 + kk2] + ((ra*128 + kel*2) ^ ((ra & 7) << 4))));
          }
          #pragma unroll
          for (int g = 0; g < 3; ++g)
            #pragma unroll
            for (int mf = 0; mf < 4; ++mf)
              acc[mf][g] = __builtin_amdgcn_mfma_f32_16x16x32_bf16(
                  af[mf], Bf[half*4 + kk2*2 + ks2][g], acc[mf][g], 0, 0, 0);
        }
      }
      if (half == 1){
        const int m0 = GROWT(t);
        #pragma unroll
        for (int mf = 0; mf < 4; ++mf){
          const int rowb = m0 + wm*64 + mf*16 + lq*4;
          f32x4 aig = acc[mf][0], afg = acc[mf][1], ahd = acc[mf][2];
          #pragma unroll
          for (int r = 0; r < 4; ++r){
            float fg = sigf(afg[r] + bfg);
            float uu = sigf(aig[r] + big) * fmaxf(ahd[r] + bhd, 0.0f);
            fu[(size_t)(rowb + r)*ROWSTR + h*Dd + dcol] = pk_bf16(fg, uu);
          }
          acc[mf][0] = (f32x4){0.f,0.f,0.f,0.f};
          acc[mf][1] = (f32x4){0.f,0.f,0.f,0.f};
          acc[mf][2] = (f32x4){0.f,0.f,0.f,0.f};
        }
      }
    }
  }
#undef GA_FETCH
#undef GA_WRITE
}

// ---- recurrence pass A: per-128-chunk (F, C) ----
__global__ void k_recur_a(const unsigned int* __restrict__ fu,
                          float* __restrict__ Fc, float* __restrict__ Cc){
  int c = blockIdx.x;
  int k = c % NCH; int hb = c / NCH;
  int b = hb / Hh, h = hb % Hh;
  int d = threadIdx.x;
  const unsigned int* p = fu + ((size_t)(b*Ss + k*CLEN)*Hh + h)*Dd + d;
  float F = 1.f, C = 0.f;
  #pragma unroll 4
  for (int i = 0; i < CLEN; ++i){
    unsigned int v = p[(size_t)i*ROWSTR];
    float f = bf2f((unsigned short)v);
    float u = bf2f((unsigned short)(v >> 16));
    C = fmaf(f, C, u);
    F *= f;
  }
  Fc[(size_t)c*Dd + d] = F;
  Cc[(size_t)c*Dd + d] = C;
}

// ---- recurrence pass B: carry BEFORE each chunk ----
__global__ void k_recur_b(const float* __restrict__ Fc, const float* __restrict__ Cc,
                          const float* __restrict__ init_cx, float* __restrict__ gcarry){
  int bh = blockIdx.x;
  int h = bh % Hh;
  int d = threadIdx.x;
  float carry = init_cx[h*Dd + d];
  for (int j = 0; j < NCH; ++j){
    size_t o = ((size_t)bh*NCH + j)*Dd + d;
    gcarry[o] = carry;
    carry = fmaf(Fc[o], carry, Cc[o]);
  }
}

// ---- fused recurrence + og GEMM + gating (R12 v2, unchanged) ----
#define CPITCH 132
#define XPITCH 136
__launch_bounds__(512, 4)
__global__ void k_og_fused(const unsigned short* __restrict__ xbf,
                           const unsigned int* __restrict__ fu,
                           const unsigned short* __restrict__ wog2,
                           const float* __restrict__ gcarry,
                           const float* __restrict__ b_og, float* __restrict__ out){
  __shared__ float s_cell[64*CPITCH];
  __shared__ unsigned short s_xa[64*XPITCH];
  __shared__ float2 s_scan[4*128];
  __shared__ float s_cc[128];
  const int mg = blockIdx.x;    // 32
  const int h  = blockIdx.y;    // 16
  const int tid = threadIdx.x;
  const int lane = tid & 63, wid = tid >> 6;
  const int wm = wid >> 2, wn = wid & 3;
  const int ln15 = lane & 15, lq = lane >> 4;
  const int rd = tid & 127, rq = tid >> 7;

  bf16x8 Bf[8][2];
  {
    const u16x8* bs8 = (const u16x8*)(wog2 + (size_t)h*(Dd*KDIM));
    #pragma unroll
    for (int ks = 0; ks < 8; ++ks)
      #pragma unroll
      for (int j = 0; j < 2; ++j)
        Bf[ks][j] = __builtin_bit_cast(bf16x8, bs8[((wn*8 + ks)*2 + j)*64 + lane]);
  }
  if (tid < 128)
    s_cc[tid] = gcarry[((size_t)((mg>>2)*Hh + h)*NCH + (mg & 3)*4)*Dd + tid];
  __syncthreads();

  f32x4 acc[2][2];
  #pragma unroll
  for (int i = 0; i < 2; ++i){ acc[i][0] = (f32x4){0,0,0,0}; acc[i][1] = (f32x4){0,0,0,0}; }

  for (int t = 0; t < 8; ++t){
    const int row0 = mg*512 + t*64;
    unsigned int uf[16];
    const unsigned int* fp = fu + (size_t)(row0 + rq*16)*ROWSTR + h*Dd + rd;
    #pragma unroll
    for (int i = 0; i < 16; ++i) uf[i] = fp[(size_t)i*ROWSTR];
    #pragma unroll
    for (int i = 0; i < 2; ++i){
      int c = tid + i*512;
      int r = c >> 4, c8 = c & 15;
      *(u16x8*)&s_xa[r*XPITCH + c8*8] =
        *(const u16x8*)(xbf + (size_t)(row0 + r)*ROWSTR + h*Aa + c8*8);
    }
    float F = 1.f, C = 0.f;
    #pragma unroll
    for (int i = 0; i < 16; ++i){
      float f = bf2f((unsigned short)uf[i]);
      float u = bf2f((unsigned short)(uf[i] >> 16));
      C = fmaf(f, C, u); F *= f;
    }
    s_scan[rq*128 + rd] = make_float2(F, C);
    __syncthreads();
    float cin = s_cc[rd];
    #pragma unroll
    for (int qq = 0; qq < 3; ++qq){
      if (rq > qq){ float2 s = s_scan[qq*128 + rd]; cin = fmaf(s.x, cin, s.y); }
    }
    __syncthreads();
    if (rq == 3){ float2 s3 = s_scan[3*128 + rd]; s_cc[rd] = fmaf(s3.x, cin, s3.y); }
    {
      float c = cin;
      #pragma unroll
      for (int i = 0; i < 16; ++i){
        float f = bf2f((unsigned short)uf[i]);
        float u = bf2f((unsigned short)(uf[i] >> 16));
        c = fmaf(f, c, u);
        s_cell[(rq*16 + i)*CPITCH + rd] = c;
      }
    }
    __syncthreads();
    #pragma unroll
    for (int ks = 0; ks < 4; ++ks){
      bf16x8 af[2];
      #pragma unroll
      for (int mf = 0; mf < 2; ++mf){
        int ra = wm*32 + mf*16 + ln15;
        af[mf] = __builtin_bit_cast(bf16x8,
          *(const u16x8*)&s_xa[ra*XPITCH + ks*32 + lq*8]);
      }
      #pragma unroll
      for (int mf = 0; mf < 2; ++mf)
        #pragma unroll
        for (int j = 0; j < 2; ++j)
          acc[mf][j] = __builtin_amdgcn_mfma_f32_16x16x32_bf16(af[mf], Bf[ks][j], acc[mf][j], 0, 0, 0);
    }
    #pragma unroll
    for (int ks = 4; ks < 8; ++ks){
      bf16x8 af[2];
      #pragma unroll
      for (int mf = 0; mf < 2; ++mf){
        int ra = wm*32 + mf*16 + ln15;
        const float* cp = &s_cell[ra*CPITCH + (ks-4)*32 + lq*8];
        f32x4 c0 = *(const f32x4*)cp;
        f32x4 c1 = *(const f32x4*)(cp + 4);
        u16x8 tt;
        tt[0]=f2bf(c0[0]); tt[1]=f2bf(c0[1]); tt[2]=f2bf(c0[2]); tt[3]=f2bf(c0[3]);
        tt[4]=f2bf(c1[0]); tt[5]=f2bf(c1[1]); tt[6]=f2bf(c1[2]); tt[7]=f2bf(c1[3]);
        af[mf] = __builtin_bit_cast(bf16x8, tt);
      }
      #pragma unroll
      for (int mf = 0; mf < 2; ++mf)
        #pragma unroll
        for (int j = 0; j < 2; ++j)
          acc[mf][j] = __builtin_amdgcn_mfma_f32_16x16x32_bf16(af[mf], Bf[ks][j], acc[mf][j], 0, 0, 0);
    }
    #pragma unroll
    for (int mf = 0; mf < 2; ++mf){
      const int rl = wm*32 + mf*16 + lq*4;
      #pragma unroll
      for (int j = 0; j < 2; ++j){
        const int d = wn*32 + j*16 + ln15;
        const float bo = b_og[h*Dd + d];
        #pragma unroll
        for (int r = 0; r < 4; ++r){
          float cell = s_cell[(rl + r)*CPITCH + d];
          out[(size_t)(row0 + rl + r)*ROWSTR + h*Dd + d] = sigf(acc[mf][j][r] + bo) * cell;
        }
        acc[mf][j] = (f32x4){0.f,0.f,0.f,0.f};
      }
    }
    __syncthreads();
  }
}

extern "C" void kernel_launch(void* const* d_in, const int* in_sizes, int n_in,
                              void* d_out, int out_size, void* d_ws, size_t ws_size,
                              hipStream_t stream){
  const float* x       = (const float*)d_in[0];
  const float* w_hid   = (const float*)d_in[1];
  const float* b_hid   = (const float*)d_in[2];
  const float* w_og    = (const float*)d_in[3];
  const float* b_og    = (const float*)d_in[4];
  const float* ln_g    = (const float*)d_in[5];
  const float* ln_b    = (const float*)d_in[6];
  const float* init_cx = (const float*)d_in[7];
  float* out = (float*)d_out;

  char* ws = (char*)d_ws;
  unsigned short* csum = (unsigned short*)(ws);                       // 64 MiB
  unsigned int*   fu   = (unsigned int*)  (ws + ((size_t)64  << 20)); // 128 MiB
  unsigned short* xbf  = (unsigned short*)(ws + ((size_t)192 << 20)); // 64 MiB
  float*          tot  = (float*)         (ws + ((size_t)256 << 20)); // 1 MiB
  float*          Fc   = (float*)         (ws + ((size_t)257 << 20)); // 1 MiB
  float*          Cc   = (float*)         (ws + ((size_t)258 << 20)); // 1 MiB
  unsigned short* wht  = (unsigned short*)(ws + ((size_t)260 << 20)); // 3 MiB
  unsigned short* wot  = (unsigned short*)(ws + ((size_t)263 << 20)); // 1 MiB
  float*          gcar = (float*)         (ws + ((size_t)264 << 20)); // 1 MiB

  k_conv_whid<<<2048, 256, 0, stream>>>(w_hid, wht);
  k_conv_wog <<<1024, 256, 0, stream>>>(w_og,  wot);
  k_cumsum_a <<<Bb*Hh*NCH, Aa, 0, stream>>>(x, tot, xbf);
  k_cumsum_c <<<Bb*Hh*NCH, Aa, 0, stream>>>(xbf, tot, csum);
  k_stats_ln <<<ROWS, 256, 0, stream>>>(csum, ln_g, ln_b);
  k_gates    <<<dim3(8, 32), 512, 0, stream>>>(xbf, csum, wht, b_hid, fu);
  k_recur_a  <<<Bb*Hh*NCH, Dd, 0, stream>>>(fu, Fc, Cc);
  k_recur_b  <<<Bb*Hh, Dd, 0, stream>>>(Fc, Cc, init_cx, gcar);
  k_og_fused <<<dim3(32, 16), 512, 0, stream>>>(xbf, fu, wot, gcar, b_og, out);
}